// Round 6
// baseline (36.169 us; speedup 1.0000x reference)
//
#include <hip/hip_runtime.h>

typedef float f32x2 __attribute__((ext_vector_type(2)));

#define NPTS 4096
#define BATCH 8
#define BLK 256
#define P 8                              // own points per thread (4 f32x2)
#define NPAIR 4
#define CHUNK 256                        // staged points per block
#define NCHUNK (NPTS / CHUNK)            // 16
#define OWN_PER_BLK (BLK * P)            // 2048
#define OWN_BLKS (NPTS / OWN_PER_BLK)    // 2 per batch
#define BLOCKS_PER_PASS (BATCH * OWN_BLKS * NCHUNK)  // 256
#define TOTAL_BLOCKS (2 * BLOCKS_PER_PASS)           // 512
#define HALF_OWN (BATCH * NPTS)          // 32768
#define TOTAL_OWN (2 * HALF_OWN)         // 65536
#define COMBINE_BLOCKS (TOTAL_OWN / BLK) // 256
#define STREAM_PTS (BATCH * NPTS)        // 32768 per direction
#define STREAM_PAD 16                    // pipeline overread slack (values unused)

// Staged point, components pre-duplicated so each is a ready packed operand.
struct Pt8 { f32x2 x, y, z, w; };        // 32 B

static __device__ __forceinline__ f32x2 splat2(float v) {
    f32x2 r; r.x = v; r.y = v; return r;
}

// Build both prescaled streams: sA = gt as (-2g, ||g||^2), sB = pred likewise.
__global__ __launch_bounds__(BLK) void chamfer_prep_kernel(
    const float* __restrict__ pred,   // [B,3,N]
    const float* __restrict__ gt,     // [B,M,3]
    Pt8* __restrict__ sA, Pt8* __restrict__ sB)
{
    const int i = blockIdx.x * BLK + threadIdx.x;   // 0..STREAM_PTS-1
    const int b = i >> 12;
    const int m = i & (NPTS - 1);

    {
        const float* gp = gt + ((size_t)b * NPTS + m) * 3;
        float gx = gp[0], gy = gp[1], gz = gp[2];
        Pt8 e;
        e.x = splat2(-2.f * gx); e.y = splat2(-2.f * gy); e.z = splat2(-2.f * gz);
        e.w = splat2(fmaf(gx, gx, fmaf(gy, gy, gz * gz)));
        sA[i] = e;
    }
    {
        const float* pp = pred + (size_t)b * 3 * NPTS;
        float px = pp[m], py = pp[NPTS + m], pz = pp[2 * NPTS + m];
        Pt8 e;
        e.x = splat2(-2.f * px); e.y = splat2(-2.f * py); e.z = splat2(-2.f * pz);
        e.w = splat2(fmaf(px, px, fmaf(py, py, pz * pz)));
        sB[i] = e;
    }
}

// D = ||p||^2 + (||q||^2 - 2 p.q); ||p||^2 added after the min.
// Staged stream is wave-uniform -> consumed via uniform (scalar) loads; the
// hot loop has ZERO DS instructions. 2-deep software pipeline, groups of 4.
__global__ __launch_bounds__(BLK, 2) void chamfer_partial_kernel(
    const float* __restrict__ pred,   // [B,3,N]
    const float* __restrict__ gt,     // [B,M,3]
    const Pt8* __restrict__ sA, const Pt8* __restrict__ sB,
    float* __restrict__ partial)      // [NCHUNK][TOTAL_OWN]
{
    const int bid  = blockIdx.x;
    const int pass = bid / BLOCKS_PER_PASS;
    int r = bid - pass * BLOCKS_PER_PASS;
    const int c = r % NCHUNK;
    r /= NCHUNK;
    const int b = r / OWN_BLKS;
    const int j = r - b * OWN_BLKS;
    const int t = threadIdx.x;

    const float* p = pred + (size_t)b * 3 * NPTS;
    const float* g = gt   + (size_t)b * NPTS * 3;
    const Pt8* __restrict__ st = (pass == 0 ? sA : sB) + (size_t)b * NPTS + c * CHUNK;

    // Own points: 8 per thread packed as 4 f32x2.
    f32x2 X[NPAIR], Y[NPAIR], Z[NPAIR], N2[NPAIR];
    #pragma unroll
    for (int k = 0; k < P; ++k) {
        int idx = j * OWN_PER_BLK + k * BLK + t;
        float x, y, z;
        if (pass == 0) {
            x = p[idx]; y = p[NPTS + idx]; z = p[2 * NPTS + idx];
        } else {
            x = g[idx * 3 + 0]; y = g[idx * 3 + 1]; z = g[idx * 3 + 2];
        }
        X[k >> 1][k & 1] = x;
        Y[k >> 1][k & 1] = y;
        Z[k >> 1][k & 1] = z;
        N2[k >> 1][k & 1] = fmaf(x, x, fmaf(y, y, z * z));
    }

    f32x2 A[NPAIR], B[NPAIR];
    #pragma unroll
    for (int pk = 0; pk < NPAIR; ++pk) { A[pk] = splat2(3.4e38f); B[pk] = splat2(3.4e38f); }

    // acc bank ACC gets one point: 3 pk_fma + 1 pk_min per own-pair.
    #define COMP(q, ACC)                                                        \
        do {                                                                    \
            _Pragma("unroll")                                                   \
            for (int pk = 0; pk < NPAIR; ++pk) {                                \
                f32x2 d = __builtin_elementwise_fma((q).x, X[pk],               \
                           __builtin_elementwise_fma((q).y, Y[pk],              \
                            __builtin_elementwise_fma((q).z, Z[pk], (q).w)));   \
                ACC[pk] = __builtin_elementwise_min(ACC[pk], d);                \
            }                                                                   \
        } while (0)

    Pt8 a0 = st[0], a1 = st[1], a2 = st[2], a3 = st[3];
    Pt8 b0, b1, b2, b3;
    #pragma unroll 1
    for (int mm = 0; mm < CHUNK; mm += 8) {
        b0 = st[mm + 4]; b1 = st[mm + 5]; b2 = st[mm + 6]; b3 = st[mm + 7];
        COMP(a0, A); COMP(a1, B); COMP(a2, A); COMP(a3, B);
        a0 = st[mm + 8]; a1 = st[mm + 9]; a2 = st[mm + 10]; a3 = st[mm + 11];
        COMP(b0, A); COMP(b1, B); COMP(b2, A); COMP(b3, B);
    }
    #undef COMP

    #pragma unroll
    for (int pk = 0; pk < NPAIR; ++pk) {
        f32x2 mn = __builtin_elementwise_min(A[pk], B[pk]);
        #pragma unroll
        for (int h = 0; h < 2; ++h) {
            int k = 2 * pk + h;
            int idx = j * OWN_PER_BLK + k * BLK + t;
            int o = pass * HALF_OWN + b * NPTS + idx;
            partial[(size_t)c * TOTAL_OWN + o] = N2[pk][h] + mn[h];
        }
    }
}

// Min over chunks per own point, then block partial sums.
__global__ __launch_bounds__(BLK) void chamfer_combine_kernel(
    const float* __restrict__ partial, float* __restrict__ bsum)
{
    __shared__ float red[BLK / 64];
    const int t = threadIdx.x;
    const int o = blockIdx.x * BLK + t;
    float v = 3.4e38f;
    #pragma unroll
    for (int c = 0; c < NCHUNK; ++c)
        v = fminf(v, partial[(size_t)c * TOTAL_OWN + o]);
    #pragma unroll
    for (int off = 32; off > 0; off >>= 1)
        v += __shfl_down(v, off, 64);
    if ((t & 63) == 0) red[t >> 6] = v;
    __syncthreads();
    if (t == 0) bsum[blockIdx.x] = red[0] + red[1] + red[2] + red[3];
}

__global__ __launch_bounds__(COMBINE_BLOCKS) void chamfer_final_kernel(
    const float* __restrict__ bsum, float* __restrict__ out)
{
    __shared__ float red[COMBINE_BLOCKS / 64];
    const int t = threadIdx.x;
    float v = bsum[t];
    #pragma unroll
    for (int off = 32; off > 0; off >>= 1)
        v += __shfl_down(v, off, 64);
    if ((t & 63) == 0) red[t >> 6] = v;
    __syncthreads();
    if (t == 0) {
        float s = 0.f;
        #pragma unroll
        for (int w = 0; w < COMBINE_BLOCKS / 64; ++w) s += red[w];
        // loss = (sum of all mins) / (NPTS * BATCH)   (N == M)
        out[0] = s * (1.0f / ((float)NPTS * (float)BATCH));
    }
}

extern "C" void kernel_launch(void* const* d_in, const int* in_sizes, int n_in,
                              void* d_out, int out_size, void* d_ws, size_t ws_size,
                              hipStream_t stream) {
    const float* pred = (const float*)d_in[0];  // [8,3,4096]
    const float* gt   = (const float*)d_in[1];  // [8,4096,3]
    float* out = (float*)d_out;

    // ws layout (floats): sA | sB | partial | bsum
    Pt8*   sA      = (Pt8*)d_ws;                                    // 32784 * 32 B
    Pt8*   sB      = sA + (STREAM_PTS + STREAM_PAD);
    float* partial = (float*)(sB + (STREAM_PTS + STREAM_PAD));      // 16*65536 floats
    float* bsum    = partial + (size_t)NCHUNK * TOTAL_OWN;          // 256 floats

    chamfer_prep_kernel<<<STREAM_PTS / BLK, BLK, 0, stream>>>(pred, gt, sA, sB);
    chamfer_partial_kernel<<<TOTAL_BLOCKS, BLK, 0, stream>>>(pred, gt, sA, sB, partial);
    chamfer_combine_kernel<<<COMBINE_BLOCKS, BLK, 0, stream>>>(partial, bsum);
    chamfer_final_kernel<<<1, COMBINE_BLOCKS, 0, stream>>>(bsum, out);
}